// Round 6
// baseline (80.374 us; speedup 1.0000x reference)
//
#include <hip/hip_runtime.h>

#define MARGIN 0.5f
#define EPS 1e-6f
#define D 256

// Zero the scalar output (poisoned 0xAA before timing, never re-poisoned
// between replays; per-block atomicAdd below requires a fresh zero each call).
__global__ void et_zero_kernel(float* __restrict__ out) {
    out[0] = 0.0f;
}

// 4 rows per group per wave. lane = r_local*16 + c_sub:
//   r_local = lane>>4 (0..3)  -> row within group
//   c_sub   = lane&15 (0..15) -> 16B chunk within a 256B row segment
// Per it: each row's 16 lanes read a contiguous 256B chunk; 4 rows per
// instruction, fully coalesced. Row reduce: 8 shuffles per 4 rows.
// BW-bound regime (R5 analysis): ~24 waves/CU x >=2 KB in flight >> the
// ~6 KB/CU Little's-law requirement, so no register pipelining needed.
// Epilogue: one fp32 atomicAdd per block, overlapped with grid drain
// (replaces the serialized 1-block reduce kernel).
__global__ __launch_bounds__(256, 8) void et_triplet_kernel(
        const float* __restrict__ x,
        const float* __restrict__ y,
        const float* __restrict__ z,
        float* __restrict__ out,
        int n_groups) {                       // n_rows / 4
    const int lane    = threadIdx.x & 63;
    const int wib     = threadIdx.x >> 6;
    const int wave    = blockIdx.x * 4 + wib;
    const int nwaves  = gridDim.x * 4;
    const int r_local = lane >> 4;            // 0..3
    const int c_sub   = lane & 15;            // 0..15

    const char* xb = (const char*)x;
    const char* yb = (const char*)y;
    const char* zb = (const char*)z;

    float acc = 0.0f;

    for (int g = wave; g < n_groups; g += nwaves) {
        const unsigned off = ((unsigned)(g * 4 + r_local) * D +
                              (unsigned)c_sub * 4) * 4u;

        float4 vx[4], vy[4], vz[4];
        #pragma unroll
        for (int it = 0; it < 4; ++it) {
            vx[it] = *reinterpret_cast<const float4*>(xb + off + it * 256);
            vy[it] = *reinterpret_cast<const float4*>(yb + off + it * 256);
            vz[it] = *reinterpret_cast<const float4*>(zb + off + it * 256);
        }

        float dp = 0.0f, dn = 0.0f;
        #pragma unroll
        for (int it = 0; it < 4; ++it) {
            float d0 = vx[it].x - vy[it].x + EPS;
            float d1 = vx[it].y - vy[it].y + EPS;
            float d2 = vx[it].z - vy[it].z + EPS;
            float d3 = vx[it].w - vy[it].w + EPS;
            dp += d0 * d0 + d1 * d1 + d2 * d2 + d3 * d3;
            float e0 = vx[it].x - vz[it].x + EPS;
            float e1 = vx[it].y - vz[it].y + EPS;
            float e2 = vx[it].z - vz[it].z + EPS;
            float e3 = vx[it].w - vz[it].w + EPS;
            dn += e0 * e0 + e1 * e1 + e2 * e2 + e3 * e3;
        }

        // Reduce over the 16 chunk-lanes of each row; 4 rows in parallel.
        dp += __shfl_xor(dp, 1, 64);  dn += __shfl_xor(dn, 1, 64);
        dp += __shfl_xor(dp, 2, 64);  dn += __shfl_xor(dn, 2, 64);
        dp += __shfl_xor(dp, 4, 64);  dn += __shfl_xor(dn, 4, 64);
        dp += __shfl_xor(dp, 8, 64);  dn += __shfl_xor(dn, 8, 64);

        const float hinge = sqrtf(dp) + MARGIN - sqrtf(dn);
        if (c_sub == 0 && hinge > 0.0f) acc += hinge;   // once per row
    }

    // Wave butterfly once per kernel, then one atomic per block.
    #pragma unroll
    for (int off = 32; off > 0; off >>= 1)
        acc += __shfl_xor(acc, off, 64);

    __shared__ float wsum[4];
    if (lane == 0) wsum[wib] = acc;
    __syncthreads();
    if (threadIdx.x == 0)
        atomicAdd(out, wsum[0] + wsum[1] + wsum[2] + wsum[3]);
}

extern "C" void kernel_launch(void* const* d_in, const int* in_sizes, int n_in,
                              void* d_out, int out_size, void* d_ws, size_t ws_size,
                              hipStream_t stream) {
    const float* x = (const float*)d_in[0];
    const float* y = (const float*)d_in[1];
    const float* z = (const float*)d_in[2];
    float* out = (float*)d_out;

    const int n_rows   = in_sizes[0] / D;    // 131072
    const int n_groups = n_rows / 4;         // 32768

    et_zero_kernel<<<1, 1, 0, stream>>>(out);

    // 2048 blocks x 4 waves = 8192 waves; 4 groups per wave, zero tail.
    const int blocks = 2048;
    et_triplet_kernel<<<blocks, 256, 0, stream>>>(x, y, z, out, n_groups);
}

// Round 7
// 73.438 us; speedup vs baseline: 1.0945x; 1.0945x over previous
//
#include <hip/hip_runtime.h>

#define MARGIN 0.5f
#define EPS 1e-6f
#define D 256

// Main kernel: 4 rows per group per wave. lane = r_local*16 + c_sub:
//   r_local = lane>>4 (0..3)  -> row within group
//   c_sub   = lane&15 (0..15) -> 16B chunk within a 256B row segment
// Per it: each row's 16 lanes read a contiguous 256B chunk; per group each
// array contributes one contiguous 4KB span. Fully coalesced.
// Row reduce: 8 shuffles per 4-row group. BW-bound (R5/R6 analysis):
// blended load path saturates at ~5.9 TB/s; occupancy/pipelining variants
// R1/R4/R5/R6 all converge here. Best structure = R4: per-block partial to
// ws (unconditional store, no init needed), tail kernel reduces partials.
__global__ __launch_bounds__(256, 8) void et_triplet_kernel(
        const float* __restrict__ x,
        const float* __restrict__ y,
        const float* __restrict__ z,
        float* __restrict__ ws,
        int n_groups) {                       // n_rows / 4
    const int lane    = threadIdx.x & 63;
    const int wib     = threadIdx.x >> 6;
    const int wave    = blockIdx.x * 4 + wib;
    const int nwaves  = gridDim.x * 4;
    const int r_local = lane >> 4;            // 0..3
    const int c_sub   = lane & 15;            // 0..15

    const char* xb = (const char*)x;
    const char* yb = (const char*)y;
    const char* zb = (const char*)z;

    float acc = 0.0f;

    for (int g = wave; g < n_groups; g += nwaves) {
        const unsigned off = ((unsigned)(g * 4 + r_local) * D +
                              (unsigned)c_sub * 4) * 4u;

        float4 vx[4], vy[4], vz[4];
        #pragma unroll
        for (int it = 0; it < 4; ++it) {
            vx[it] = *reinterpret_cast<const float4*>(xb + off + it * 256);
            vy[it] = *reinterpret_cast<const float4*>(yb + off + it * 256);
            vz[it] = *reinterpret_cast<const float4*>(zb + off + it * 256);
        }

        float dp = 0.0f, dn = 0.0f;
        #pragma unroll
        for (int it = 0; it < 4; ++it) {
            float d0 = vx[it].x - vy[it].x + EPS;
            float d1 = vx[it].y - vy[it].y + EPS;
            float d2 = vx[it].z - vy[it].z + EPS;
            float d3 = vx[it].w - vy[it].w + EPS;
            dp += d0 * d0 + d1 * d1 + d2 * d2 + d3 * d3;
            float e0 = vx[it].x - vz[it].x + EPS;
            float e1 = vx[it].y - vz[it].y + EPS;
            float e2 = vx[it].z - vz[it].z + EPS;
            float e3 = vx[it].w - vz[it].w + EPS;
            dn += e0 * e0 + e1 * e1 + e2 * e2 + e3 * e3;
        }

        // Reduce over the 16 chunk-lanes of each row; 4 rows in parallel.
        dp += __shfl_xor(dp, 1, 64);  dn += __shfl_xor(dn, 1, 64);
        dp += __shfl_xor(dp, 2, 64);  dn += __shfl_xor(dn, 2, 64);
        dp += __shfl_xor(dp, 4, 64);  dn += __shfl_xor(dn, 4, 64);
        dp += __shfl_xor(dp, 8, 64);  dn += __shfl_xor(dn, 8, 64);

        const float hinge = sqrtf(dp) + MARGIN - sqrtf(dn);
        if (c_sub == 0 && hinge > 0.0f) acc += hinge;   // once per row
    }

    // Wave butterfly once per kernel, then one store per block.
    #pragma unroll
    for (int off = 32; off > 0; off >>= 1)
        acc += __shfl_xor(acc, off, 64);

    __shared__ float wsum[4];
    if (lane == 0) wsum[wib] = acc;
    __syncthreads();
    if (threadIdx.x == 0)
        ws[blockIdx.x] = wsum[0] + wsum[1] + wsum[2] + wsum[3];
}

// Tail: reduce n_partials floats (multiple of 1024 = 256 threads x float4)
// from ws into out[0]. Unconditional overwrite -> no zero-init dispatch.
__global__ __launch_bounds__(256) void et_reduce_kernel(
        const float* __restrict__ ws, float* __restrict__ out, int n_partials) {
    const int lane = threadIdx.x & 63;
    const int wib  = threadIdx.x >> 6;
    float s = 0.0f;
    for (int i = threadIdx.x * 4; i < n_partials; i += 256 * 4) {
        const float4 v = *reinterpret_cast<const float4*>(ws + i);
        s += (v.x + v.y) + (v.z + v.w);
    }
    #pragma unroll
    for (int off = 32; off > 0; off >>= 1)
        s += __shfl_xor(s, off, 64);
    __shared__ float wsum[4];
    if (lane == 0) wsum[wib] = s;
    __syncthreads();
    if (threadIdx.x == 0)
        out[0] = wsum[0] + wsum[1] + wsum[2] + wsum[3];
}

extern "C" void kernel_launch(void* const* d_in, const int* in_sizes, int n_in,
                              void* d_out, int out_size, void* d_ws, size_t ws_size,
                              hipStream_t stream) {
    const float* x = (const float*)d_in[0];
    const float* y = (const float*)d_in[1];
    const float* z = (const float*)d_in[2];
    float* out = (float*)d_out;
    float* ws  = (float*)d_ws;

    const int n_rows   = in_sizes[0] / D;    // 131072
    const int n_groups = n_rows / 4;         // 32768

    // 2048 blocks x 4 waves = 8192 waves; 4 groups per wave, zero tail.
    const int blocks = 2048;
    et_triplet_kernel<<<blocks, 256, 0, stream>>>(x, y, z, ws, n_groups);
    et_reduce_kernel<<<1, 256, 0, stream>>>(ws, out, blocks);
}